// Round 4
// baseline (351.260 us; speedup 1.0000x reference)
//
#include <hip/hip_runtime.h>

// ---------------------------------------------------------------------------
// CanonicalLinear: out[b,c] = sum_n factor[n] * (x @ W[n]^T + b[n])[b,c]
// Collapse heads: Weff = sum_n factor[n]*W[n] (C x D), beff = sum_n factor[n]*b[n]
// then out = x @ Weff^T + beff.
// Round 4: x-cast round-trip eliminated -- GEMM stages fp32 x straight into a
//          32 KB XOR-swizzled LDS tile via global_load_lds and packs to bf16
//          at fragment read (v_perm truncation, 1 op per pair). Prep is now
//          W-reduce + bias only (142 MB irreducible traffic).
// ---------------------------------------------------------------------------

#define MDIM 8192
#define KDIM 2048
#define NDIM 2048
#define NHEADS 8

#define BM 128
#define BN 128
#define BK 64

using bf16x8 = __attribute__((ext_vector_type(8))) short;
using f32x4  = __attribute__((ext_vector_type(4))) float;

__device__ __forceinline__ unsigned short f2bf(float x) {   // RNE (prep only)
    unsigned int u = __float_as_uint(x);
    u += 0x7FFFu + ((u >> 16) & 1u);
    return (unsigned short)(u >> 16);
}

// pack two fp32 -> two bf16 (truncate): dst = {hi16(hi), hi16(lo)}
__device__ __forceinline__ unsigned int pk_trunc(float hi, float lo) {
    return __builtin_amdgcn_perm(__float_as_uint(hi), __float_as_uint(lo),
                                 0x07060302u);
}

__device__ __forceinline__ void async_load16(const void* g, void* l) {
    __builtin_amdgcn_global_load_lds(
        (const __attribute__((address_space(1))) unsigned int*)g,
        (__attribute__((address_space(3))) unsigned int*)l,
        16, 0, 0);
}

// --- prep: Wbf[c,d] = bf16_rne(sum_n f[n]*W[n,c,d]); beff = sum_n f[n]*b[n] -
// 2048 blocks x 256 threads; 8 elems/thread; all 16 loads issued before FMAs.
__global__ __launch_bounds__(256) void prep_kernel(
    const float* __restrict__ W,
    const float* __restrict__ b,
    const float* __restrict__ factor,
    unsigned short* __restrict__ Wbf,
    float* __restrict__ beff) {
    const int gtid = blockIdx.x * 256 + threadIdx.x;    // 0 .. 524,287
    const size_t CD = (size_t)NDIM * KDIM;
    const size_t base = (size_t)gtid * 8;

    float f[NHEADS];
#pragma unroll
    for (int n = 0; n < NHEADS; ++n) f[n] = factor[n];

    float4 L[16];
#pragma unroll
    for (int n = 0; n < NHEADS; ++n) {
        L[2 * n]     = *reinterpret_cast<const float4*>(W + (size_t)n * CD + base);
        L[2 * n + 1] = *reinterpret_cast<const float4*>(W + (size_t)n * CD + base + 4);
    }

    float a0 = 0.f, a1 = 0.f, a2 = 0.f, a3 = 0.f;
    float a4 = 0.f, a5 = 0.f, a6 = 0.f, a7 = 0.f;
#pragma unroll
    for (int n = 0; n < NHEADS; ++n) {
        a0 += f[n] * L[2 * n].x;     a1 += f[n] * L[2 * n].y;
        a2 += f[n] * L[2 * n].z;     a3 += f[n] * L[2 * n].w;
        a4 += f[n] * L[2 * n + 1].x; a5 += f[n] * L[2 * n + 1].y;
        a6 += f[n] * L[2 * n + 1].z; a7 += f[n] * L[2 * n + 1].w;
    }
    union { unsigned short u[8]; uint4 q; } o;
    o.u[0] = f2bf(a0); o.u[1] = f2bf(a1); o.u[2] = f2bf(a2); o.u[3] = f2bf(a3);
    o.u[4] = f2bf(a4); o.u[5] = f2bf(a5); o.u[6] = f2bf(a6); o.u[7] = f2bf(a7);
    *reinterpret_cast<uint4*>(Wbf + base) = o.q;

    if (gtid < NDIM) {
        float s = 0.f;
#pragma unroll
        for (int n = 0; n < NHEADS; ++n) s += factor[n] * b[(size_t)n * NDIM + gtid];
        beff[gtid] = s;
    }
}

// --- GEMM: out[m,c] = sum_k x[m,k]*Wbf[c,k] + beff[c] -----------------------
// A staged as fp32 (32 KB LDS, 16-B-granule XOR swizzle by row&15), packed to
// bf16 at fragment read. B staged bf16 as before (XOR by row&7).
__global__ __launch_bounds__(256) void gemm_bt_kernel(
    const float* __restrict__ A,            // x    [MDIM][KDIM] fp32
    const unsigned short* __restrict__ B,   // Wbf  [NDIM][KDIM] bf16
    const float* __restrict__ bias,         // beff [NDIM]
    float* __restrict__ C)                  // out  [MDIM][NDIM] fp32
{
    __shared__ float          As[BM * BK];  // 32 KB fp32
    __shared__ unsigned short Bs[BN * BK];  // 16 KB bf16

    const int tid  = threadIdx.x;
    const int lane = tid & 63;
    const int w    = tid >> 6;      // wave 0..3
    const int m16  = lane & 15;
    const int quad = lane >> 4;     // 0..3

    // XCD-aware swizzle: xcd = bid&7 owns N-tiles {2*xcd, 2*xcd+1}
    const int bid = blockIdx.x;
    const int g   = bid >> 3;
    const int nt  = (bid & 7) * 2 + (g & 1);
    const int mt  = g >> 1;
    const int blockN0 = nt * BN;
    const int blockM0 = mt * BM;

    const int wr = (w >> 1) * 64;
    const int wc = (w & 1) * 64;

    // ---- A staging (fp32): 8 chunks/wave, chunk i = rows [i*16 + w*4, +4).
    // LDS slot (row, gran) holds global granule gran ^ (row & 15); row&15 of
    // a staged row is exactly w*4 + (lane>>4).
    const int sArow = lane >> 4;                 // 0..3
    const int sAgr  = lane & 15;                 // 16-B granule 0..15
    const int rmodA = w * 4 + sArow;             // == row & 15
    const int gcolA = (sAgr ^ rmodA) * 4;        // fp32 col within BK
    const float* aP[8];
    float* aL[8];
#pragma unroll
    for (int i = 0; i < 8; ++i) {
        int r = i * 16 + w * 4;
        aP[i] = A + (size_t)(blockM0 + r + sArow) * KDIM + gcolA;
        aL[i] = As + (size_t)r * BK;             // wave-uniform base
    }

    // ---- B staging (bf16): 4 chunks/wave, XOR by row&7 (as round 2/3).
    const int sBrow = lane >> 3;                 // 0..7
    const int sBcol = ((lane & 7) ^ sBrow) * 8;  // bf16 col
    const unsigned short* bP[4];
    unsigned short* bL[4];
#pragma unroll
    for (int i = 0; i < 4; ++i) {
        int r = i * 32 + w * 8;
        bP[i] = B + (size_t)(blockN0 + r + sBrow) * KDIM + sBcol;
        bL[i] = Bs + (size_t)r * BK;
    }

    f32x4 acc[4][4] = {};

    for (int k0 = 0; k0 < KDIM; k0 += BK) {
#pragma unroll
        for (int i = 0; i < 8; ++i) { async_load16(aP[i], aL[i]); aP[i] += BK; }
#pragma unroll
        for (int i = 0; i < 4; ++i) { async_load16(bP[i], bL[i]); bP[i] += BK; }
        __syncthreads();

#pragma unroll
        for (int kk = 0; kk < BK; kk += 32) {
            bf16x8 af[4], bfr[4];
#pragma unroll
            for (int rt = 0; rt < 4; ++rt) {
                int row = wr + rt * 16 + m16;          // row & 15 == m16
                int g0  = (kk >> 2) + quad * 2;        // global granule base
                const float4 lo = *reinterpret_cast<const float4*>(
                    &As[(size_t)row * BK + ((g0)     ^ m16) * 4]);
                const float4 hi = *reinterpret_cast<const float4*>(
                    &As[(size_t)row * BK + ((g0 + 1) ^ m16) * 4]);
                union { bf16x8 v; unsigned int u[4]; } t;
                t.u[0] = pk_trunc(lo.y, lo.x);
                t.u[1] = pk_trunc(lo.w, lo.z);
                t.u[2] = pk_trunc(hi.y, hi.x);
                t.u[3] = pk_trunc(hi.w, hi.z);
                af[rt] = t.v;
            }
#pragma unroll
            for (int ct = 0; ct < 4; ++ct) {
                int row = wc + ct * 16 + m16;
                int gB = ((kk >> 3) + quad) ^ (row & 7);
                bfr[ct] = *reinterpret_cast<const bf16x8*>(&Bs[(size_t)row * BK + gB * 8]);
            }
#pragma unroll
            for (int rt = 0; rt < 4; ++rt)
#pragma unroll
                for (int ct = 0; ct < 4; ++ct)
                    acc[rt][ct] = __builtin_amdgcn_mfma_f32_16x16x32_bf16(
                        af[rt], bfr[ct], acc[rt][ct], 0, 0, 0);
        }
        __syncthreads();
    }

    // epilogue: C/D layout col=lane&15, row=quad*4+reg (verified m89/m91)
    float bv[4];
#pragma unroll
    for (int ct = 0; ct < 4; ++ct) bv[ct] = bias[blockN0 + wc + ct * 16 + m16];
#pragma unroll
    for (int rt = 0; rt < 4; ++rt) {
        int row0 = blockM0 + wr + rt * 16 + quad * 4;
#pragma unroll
        for (int ct = 0; ct < 4; ++ct) {
            int col = blockN0 + wc + ct * 16 + m16;
#pragma unroll
            for (int r = 0; r < 4; ++r)
                C[(size_t)(row0 + r) * NDIM + col] = acc[rt][ct][r] + bv[ct];
        }
    }
}

extern "C" void kernel_launch(void* const* d_in, const int* in_sizes, int n_in,
                              void* d_out, int out_size, void* d_ws, size_t ws_size,
                              hipStream_t stream) {
    const float* x      = (const float*)d_in[0];   // [8192][2048]
    const float* W      = (const float*)d_in[1];   // [8][2048][2048]
    const float* b      = (const float*)d_in[2];   // [8][2048]
    const float* factor = (const float*)d_in[3];   // [8]
    float* out = (float*)d_out;                    // [8192][2048]

    unsigned short* Wbf  = (unsigned short*)d_ws;                  // 8,388,608 B
    float*          beff = (float*)((char*)d_ws + 8388608);        //     8,192 B

    prep_kernel<<<dim3(2048), dim3(256), 0, stream>>>(W, b, factor, Wbf, beff);
    gemm_bt_kernel<<<dim3(1024), dim3(256), 0, stream>>>(x, Wbf, beff, out);
}